// Round 2
// baseline (148.781 us; speedup 1.0000x reference)
//
#include <hip/hip_runtime.h>
#include <math.h>

// LeNet-ish forward, fp32, B=8192.
// S-trick: pool2x2(conv5x5(x)) computed as stride-2 5x5 correlation over
// S(y,x) = 2x2-window-sum of input -> 4x fewer MACs.
//
// ws layout: [w2q transpose 20KB pad->32KB][h1: 8192*1440 f32][h2: 8192*320 f32]

#define IMG1 8
#define IMG2 8

__device__ __forceinline__ float sigf(float v) {
    return 1.0f / (1.0f + __expf(-v));
}

// --- K0: repack W2 [c][ic][ky][kx] -> w2q [ic][ky][c][kx] (for float4 loads) ---
__global__ void k_w2t(const float* __restrict__ W2, float* __restrict__ w2q) {
    int i = blockIdx.x * 256 + threadIdx.x;
    if (i < 5000) {
        int kx = i % 5, t = i / 5;
        int ky = t % 5, t2 = t / 5;
        int ic = t2 % 10, c = t2 / 10;
        w2q[((ic * 5 + ky) * 20 + c) * 5 + kx] = W2[i];
    }
}

// --- K1: conv1(5x5,1->10) + avgpool2 + sigmoid.  x[B,1,28,28] -> h1[B,10,12,12]
// block=192: 8 images x (2 cgroups of 5 ch) x (12 pooled rows)
__global__ __launch_bounds__(192) void k_conv1(
    const float* __restrict__ x, const float* __restrict__ W1,
    const float* __restrict__ b1, float* __restrict__ h1) {
    __shared__ float S[IMG1][27][28];   // 2x2 window sums, col 27 = pad (unused)
    __shared__ float wq[5][10][8];      // [ky][c][kx] padded to 8 for alignment
    __shared__ float bs[10];

    const int tid = threadIdx.x;
    // FIX r1: W1 has 250 elements but block=192 -> must grid-stride, the old
    // `if (tid < 250)` left weights 192..249 (channels 7-9) uninitialized.
    for (int i = tid; i < 250; i += 192) {
        int c = i / 25, r = i % 25, ky = r / 5, kx = r % 5;
        wq[ky][c][kx] = W1[i];
    }
    if (tid < 10) bs[tid] = b1[tid];

    const long img0 = (long)blockIdx.x * IMG1;
    for (int i = tid; i < IMG1 * 729; i += 192) {
        int im = i / 729, r = i % 729, y = r / 27, xx = r % 27;
        const float* xp = x + (img0 + im) * 784 + y * 28 + xx;
        S[im][y][xx] = xp[0] + xp[1] + xp[28] + xp[29];
    }
    __syncthreads();

    const int im = tid / 24, r2 = tid % 24, cg = r2 / 12, py = r2 % 12;
    float acc[5][12];
#pragma unroll
    for (int a = 0; a < 5; ++a)
#pragma unroll
        for (int b = 0; b < 12; ++b) acc[a][b] = 0.f;

#pragma unroll
    for (int ky = 0; ky < 5; ++ky) {
        union { float4 v[7]; float f[28]; } R;
        const float4* rp = (const float4*)&S[im][2 * py + ky][0];
#pragma unroll
        for (int q = 0; q < 7; ++q) R.v[q] = rp[q];
#pragma unroll
        for (int cc = 0; cc < 5; ++cc) {
            const int c = cg * 5 + cc;
            union { float4 v; float f[4]; } W4;
            W4.v = *(const float4*)&wq[ky][c][0];
            const float w4 = wq[ky][c][4];
#pragma unroll
            for (int kx = 0; kx < 5; ++kx) {
                const float wv = (kx < 4) ? W4.f[kx] : w4;
#pragma unroll
                for (int px = 0; px < 12; ++px)
                    acc[cc][px] += R.f[2 * px + kx] * wv;
            }
        }
    }

    float* outp = h1 + (img0 + im) * 1440 + (cg * 5) * 144 + py * 12;
#pragma unroll
    for (int cc = 0; cc < 5; ++cc) {
        union { float4 v[3]; float f[12]; } O;
#pragma unroll
        for (int px = 0; px < 12; ++px) {
            float v = acc[cc][px] * 0.25f + bs[cg * 5 + cc];
            O.f[px] = sigf(v);
        }
        float4* op = (float4*)(outp + cc * 144);
        op[0] = O.v[0]; op[1] = O.v[1]; op[2] = O.v[2];
    }
}

// --- K2: conv2(5x5,10->20) + avgpool2 + sigmoid. h1[B,10,12,12] -> h2[B,320]
// block=192 (160 active in compute): 8 img x (5 cgroups of 4 ch) x (4 pooled rows)
__global__ __launch_bounds__(192) void k_conv2(
    const float* __restrict__ h1, const float* __restrict__ w2q,
    const float* __restrict__ b2, float* __restrict__ h2) {
    __shared__ float S1[IMG2][10][11][12];  // col 11 = pad (unused)
    __shared__ float bs[20];

    const int tid = threadIdx.x;
    if (tid < 20) bs[tid] = b2[tid];

    const long img0 = (long)blockIdx.x * IMG2;
    for (int i = tid; i < IMG2 * 1210; i += 192) {
        int im = i / 1210, r = i % 1210;
        int ic = r / 121, r2 = r % 121, y = r2 / 11, xx = r2 % 11;
        const float* p = h1 + (img0 + im) * 1440 + ic * 144 + y * 12 + xx;
        S1[im][ic][y][xx] = p[0] + p[1] + p[12] + p[13];
    }
    __syncthreads();

    if (tid >= 160) return;  // no further barriers
    const int im = tid / 20, r2 = tid % 20, cg = r2 / 4, py = r2 % 4;

    float acc[4][4];
#pragma unroll
    for (int a = 0; a < 4; ++a)
#pragma unroll
        for (int b = 0; b < 4; ++b) acc[a][b] = 0.f;

    for (int ic = 0; ic < 10; ++ic) {
#pragma unroll
        for (int ky = 0; ky < 5; ++ky) {
            union { float4 v[3]; float f[12]; } R;
            const float4* rp = (const float4*)&S1[im][ic][2 * py + ky][0];
            R.v[0] = rp[0]; R.v[1] = rp[1]; R.v[2] = rp[2];
            union { float4 v[5]; float f[20]; } W;
            const float4* wp = (const float4*)(w2q + (ic * 5 + ky) * 100 + cg * 20);
#pragma unroll
            for (int q = 0; q < 5; ++q) W.v[q] = wp[q];
#pragma unroll
            for (int cc = 0; cc < 4; ++cc)
#pragma unroll
                for (int kx = 0; kx < 5; ++kx) {
                    const float wv = W.f[cc * 5 + kx];
#pragma unroll
                    for (int px = 0; px < 4; ++px)
                        acc[cc][px] += R.f[2 * px + kx] * wv;
                }
        }
    }

    float* outp = h2 + (img0 + im) * 320 + (cg * 4) * 16 + py * 4;
#pragma unroll
    for (int cc = 0; cc < 4; ++cc) {
        union { float4 v; float f[4]; } O;
#pragma unroll
        for (int px = 0; px < 4; ++px) {
            float v = acc[cc][px] * 0.25f + bs[cg * 4 + cc];
            O.f[px] = sigf(v);
        }
        *(float4*)(outp + cc * 16) = O.v;
    }
}

// --- K3: FC chain 320->120->84->10 (sigmoid, sigmoid, none). 8 img/block. ---
__global__ __launch_bounds__(256) void k_fc(
    const float* __restrict__ h2, const float* __restrict__ L1,
    const float* __restrict__ Lb1, const float* __restrict__ L2,
    const float* __restrict__ Lb2, const float* __restrict__ L3,
    const float* __restrict__ Lb3, float* __restrict__ out) {
    __shared__ float h2s[8][324];  // pad: 324%32=4 -> img rows on distinct banks
    __shared__ float g1s[8][124];
    __shared__ float g2s[8][88];

    const int tid = threadIdx.x;
    const long img0 = (long)blockIdx.x * 8;

    for (int idx = tid; idx < 640; idx += 256) {
        float4 v = ((const float4*)(h2 + img0 * 320))[idx];
        int im = idx / 80, off = (idx % 80) * 4;
        *(float4*)&h2s[im][off] = v;
    }
    __syncthreads();

    const int jg = tid >> 3, img = tid & 7;

    if (jg < 30) {  // FC1: 120 outputs = 30 groups of 4
        union { float4 v; float f[4]; } A;
        A.v = *(const float4*)(Lb1 + jg * 4);
        for (int i4 = 0; i4 < 80; ++i4) {
            union { float4 v; float f[4]; } H;
            H.v = *(const float4*)&h2s[img][i4 * 4];
#pragma unroll
            for (int di = 0; di < 4; ++di) {
                float4 w = ((const float4*)L1)[(i4 * 4 + di) * 30 + jg];
                A.f[0] += H.f[di] * w.x;
                A.f[1] += H.f[di] * w.y;
                A.f[2] += H.f[di] * w.z;
                A.f[3] += H.f[di] * w.w;
            }
        }
#pragma unroll
        for (int q = 0; q < 4; ++q) A.f[q] = sigf(A.f[q]);
        *(float4*)&g1s[img][jg * 4] = A.v;
    }
    __syncthreads();

    if (jg < 21) {  // FC2: 84 outputs = 21 groups of 4
        union { float4 v; float f[4]; } A;
        A.v = *(const float4*)(Lb2 + jg * 4);
        for (int i4 = 0; i4 < 30; ++i4) {
            union { float4 v; float f[4]; } H;
            H.v = *(const float4*)&g1s[img][i4 * 4];
#pragma unroll
            for (int di = 0; di < 4; ++di) {
                float4 w = ((const float4*)L2)[(i4 * 4 + di) * 21 + jg];
                A.f[0] += H.f[di] * w.x;
                A.f[1] += H.f[di] * w.y;
                A.f[2] += H.f[di] * w.z;
                A.f[3] += H.f[di] * w.w;
            }
        }
#pragma unroll
        for (int q = 0; q < 4; ++q) A.f[q] = sigf(A.f[q]);
        *(float4*)&g2s[img][jg * 4] = A.v;
    }
    __syncthreads();

    if (tid < 80) {  // FC3: 10 outputs, scalar
        int im = tid / 10, j = tid % 10;
        float a = Lb3[j];
        for (int i = 0; i < 84; ++i) a += g2s[im][i] * L3[i * 10 + j];
        out[(img0 + im) * 10 + j] = a;
    }
}

extern "C" void kernel_launch(void* const* d_in, const int* in_sizes, int n_in,
                              void* d_out, int out_size, void* d_ws, size_t ws_size,
                              hipStream_t stream) {
    const float* x   = (const float*)d_in[0];
    const float* W1  = (const float*)d_in[1];
    const float* b1  = (const float*)d_in[2];
    const float* W2  = (const float*)d_in[3];
    const float* b2  = (const float*)d_in[4];
    const float* L1  = (const float*)d_in[5];
    const float* Lb1 = (const float*)d_in[6];
    const float* L2  = (const float*)d_in[7];
    const float* Lb2 = (const float*)d_in[8];
    const float* L3  = (const float*)d_in[9];
    const float* Lb3 = (const float*)d_in[10];
    float* out = (float*)d_out;

    const int B = in_sizes[0] / 784;  // 8192

    char* ws = (char*)d_ws;
    float* w2q = (float*)ws;
    float* h1  = (float*)(ws + 32768);
    float* h2  = (float*)(ws + 32768 + (size_t)B * 1440 * 4);

    hipLaunchKernelGGL(k_w2t, dim3(20), dim3(256), 0, stream, W2, w2q);
    hipLaunchKernelGGL(k_conv1, dim3(B / IMG1), dim3(192), 0, stream, x, W1, b1, h1);
    hipLaunchKernelGGL(k_conv2, dim3(B / IMG2), dim3(192), 0, stream, h1, w2q, b2, h2);
    hipLaunchKernelGGL(k_fc, dim3(B / 8), dim3(256), 0, stream,
                       h2, L1, Lb1, L2, Lb2, L3, Lb3, out);
}

// Round 3
// 135.081 us; speedup vs baseline: 1.1014x; 1.1014x over previous
//
#include <hip/hip_runtime.h>
#include <math.h>

// LeNet-ish forward, fp32, B=8192.
// S-trick: pool2x2(conv5x5(v)) == (1/4) * stride-2 5x5 correlation over
// S(y,x) = v(y,x)+v(y,x+1)+v(y+1,x)+v(y+1,x+1).
// conv1 emits S1 (window-sum of its sigmoid output) directly, so conv2 needs
// no per-element gather; h1 never exists in memory.
//
// ws: [w2q 32KB][L2p 64KB pad][S1: B*1320 f32][h2: B*320 f32]

__device__ __forceinline__ float sigf(float v) {
    return 1.0f / (1.0f + __expf(-v));
}

// --- K0: repack W2 [c][ic][ky][kx] -> w2q [ic][ky][c][kx]; pad L2 [120][84]->[120][88]
__global__ void k_prep(const float* __restrict__ W2, const float* __restrict__ L2,
                       float* __restrict__ w2q, float* __restrict__ L2p) {
    int i = blockIdx.x * 256 + threadIdx.x;
    if (i < 5000) {
        int kx = i % 5, t = i / 5;
        int ky = t % 5, t2 = t / 5;
        int ic = t2 % 10, c = t2 / 10;
        w2q[((ic * 5 + ky) * 20 + c) * 5 + kx] = W2[i];
    }
    int j = i - 5000;
    if (j >= 0 && j < 10080) {
        L2p[(j / 84) * 88 + (j % 84)] = L2[j];
    }
}

// --- K1: conv1 + pool + sigmoid + window-sum.  x[B,1,28,28] -> S1g[B,10,11,12]
// block=256 = 16 groups of 16 lanes; group g=(im,cg), lane l=py (12 active).
// Lane groups of 16 never straddle a wave64 -> __shfl_down(.,1,16) gives py+1.
__global__ __launch_bounds__(256) void k_conv1(
    const float* __restrict__ x, const float* __restrict__ W1,
    const float* __restrict__ b1, float* __restrict__ S1g) {
    __shared__ float XR[8][784];     // raw x tile (25.1KB)
    __shared__ float S[8][27][28];   // 2x2 window sums of x (24.2KB)
    __shared__ float wq[5][10][8];
    __shared__ float bs[10];

    const int tid = threadIdx.x;
    for (int i = tid; i < 250; i += 256) {
        int c = i / 25, r = i % 25;
        wq[r / 5][c][r % 5] = W1[i];
    }
    if (tid < 10) bs[tid] = b1[tid];

    const long img0 = (long)blockIdx.x * 8;
    {
        const float4* xg = (const float4*)(x + img0 * 784);
        float4* xl = (float4*)XR;
        for (int i = tid; i < 1568; i += 256) xl[i] = xg[i];
    }
    __syncthreads();

    // S from XR, thread-local horizontal reuse: 2 new reads per element
    for (int t = tid; t < 216; t += 256) {
        int im = t / 27, y = t % 27;
        const float* r0 = &XR[im][y * 28];
        const float* r1 = r0 + 28;
        float a0 = r0[0] + r1[0];
        float* so = &S[im][y][0];
#pragma unroll
        for (int xx = 0; xx < 27; ++xx) {
            float a1 = r0[xx + 1] + r1[xx + 1];
            so[xx] = a0 + a1;
            a0 = a1;
        }
    }
    __syncthreads();

    const int g = tid >> 4, l = tid & 15, im = g >> 1, cg = g & 1;
    if (l < 12) {
        const int py = l;
        float acc[5][12];
#pragma unroll
        for (int a = 0; a < 5; ++a)
#pragma unroll
            for (int b = 0; b < 12; ++b) acc[a][b] = 0.f;

#pragma unroll
        for (int ky = 0; ky < 5; ++ky) {
            union { float4 v[7]; float f[28]; } R;
            const float4* rp = (const float4*)&S[im][2 * py + ky][0];
#pragma unroll
            for (int q = 0; q < 7; ++q) R.v[q] = rp[q];
#pragma unroll
            for (int cc = 0; cc < 5; ++cc) {
                const int c = cg * 5 + cc;
                union { float4 v; float f[4]; } W4;
                W4.v = *(const float4*)&wq[ky][c][0];
                const float w4 = wq[ky][c][4];
#pragma unroll
                for (int kx = 0; kx < 5; ++kx) {
                    const float wv = (kx < 4) ? W4.f[kx] : w4;
#pragma unroll
                    for (int px = 0; px < 12; ++px)
                        acc[cc][px] += R.f[2 * px + kx] * wv;
                }
            }
        }

        // h row (12), horizontal pair-sum hh (11), vertical via shuffle
        float hh[5][11];
#pragma unroll
        for (int cc = 0; cc < 5; ++cc) {
            float h[12];
#pragma unroll
            for (int px = 0; px < 12; ++px)
                h[px] = sigf(acc[cc][px] * 0.25f + bs[cg * 5 + cc]);
#pragma unroll
            for (int xx = 0; xx < 11; ++xx) hh[cc][xx] = h[xx] + h[xx + 1];
        }
#pragma unroll
        for (int cc = 0; cc < 5; ++cc) {
            union { float4 v[3]; float f[12]; } O;
#pragma unroll
            for (int xx = 0; xx < 11; ++xx)
                O.f[xx] = hh[cc][xx] + __shfl_down(hh[cc][xx], 1, 16);
            O.f[11] = 0.f;
            if (py < 11) {  // S1 has 11 rows; py=11's shuffle result is discarded
                float* sp = S1g + ((img0 + im) * 10 + cg * 5 + cc) * 132 + py * 12;
                float4* op = (float4*)sp;
                op[0] = O.v[0]; op[1] = O.v[1]; op[2] = O.v[2];
            }
        }
    }
}

// --- K2: conv2 + pool + sigmoid. S1g[B,10,11,12] -> h2[B,320]
// block=192 (160 active in compute): 8 img x (5 cgroups of 4 ch) x (4 pooled rows)
__global__ __launch_bounds__(192) void k_conv2(
    const float* __restrict__ S1g, const float* __restrict__ w2q,
    const float* __restrict__ b2, float* __restrict__ h2) {
    __shared__ float S1t[8][10][132];  // 42.2KB
    __shared__ float bs[20];

    const int tid = threadIdx.x;
    if (tid < 20) bs[tid] = b2[tid];

    const long img0 = (long)blockIdx.x * 8;
    {
        const float4* sg = (const float4*)(S1g + img0 * 1320);
        float4* sl = (float4*)S1t;
        for (int i = tid; i < 2640; i += 192) sl[i] = sg[i];
    }
    __syncthreads();

    if (tid >= 160) return;  // no further barriers
    const int im = tid / 20, r2 = tid % 20, cg = r2 / 4, py = r2 % 4;

    float acc[4][4];
#pragma unroll
    for (int a = 0; a < 4; ++a)
#pragma unroll
        for (int b = 0; b < 4; ++b) acc[a][b] = 0.f;

    for (int ic = 0; ic < 10; ++ic) {
#pragma unroll
        for (int ky = 0; ky < 5; ++ky) {
            union { float4 v[3]; float f[12]; } R;
            const float4* rp = (const float4*)&S1t[im][ic][(2 * py + ky) * 12];
            R.v[0] = rp[0]; R.v[1] = rp[1]; R.v[2] = rp[2];
            union { float4 v[5]; float f[20]; } W;
            const float4* wp = (const float4*)(w2q + (ic * 5 + ky) * 100 + cg * 20);
#pragma unroll
            for (int q = 0; q < 5; ++q) W.v[q] = wp[q];
#pragma unroll
            for (int cc = 0; cc < 4; ++cc)
#pragma unroll
                for (int kx = 0; kx < 5; ++kx) {
                    const float wv = W.f[cc * 5 + kx];
#pragma unroll
                    for (int px = 0; px < 4; ++px)
                        acc[cc][px] += R.f[2 * px + kx] * wv;
                }
        }
    }

    float* outp = h2 + (img0 + im) * 320 + (cg * 4) * 16 + py * 4;
#pragma unroll
    for (int cc = 0; cc < 4; ++cc) {
        union { float4 v; float f[4]; } O;
#pragma unroll
        for (int px = 0; px < 4; ++px)
            O.f[px] = sigf(acc[cc][px] * 0.25f + bs[cg * 4 + cc]);
        *(float4*)(outp + cc * 16) = O.v;
    }
}

// --- K3: FC chain, 16 images/block, 4out x 4img register tiles. ---
// Activations row-major in LDS (scalar reads, f4-aligned rows; odd-ish pads
// so the 4 img-lanes land on distinct banks). Weights stream from L2.
__global__ __launch_bounds__(128) void k_fc(
    const float* __restrict__ h2, const float* __restrict__ L1,
    const float* __restrict__ Lb1, const float* __restrict__ L2p,
    const float* __restrict__ Lb2, const float* __restrict__ L3,
    const float* __restrict__ Lb3, float* __restrict__ out) {
    __shared__ float h2n[16][324];  // 20.7KB; 324%32=4
    __shared__ float g1n[16][121];  // 121%32=25 -> img offsets hit distinct banks
    __shared__ float g2n[16][85];

    const int tid = threadIdx.x;
    const long img0 = (long)blockIdx.x * 16;

    {
        const float4* hg = (const float4*)(h2 + img0 * 320);
        for (int i = tid; i < 1280; i += 128) {
            int im = i / 80, i0 = (i % 80) * 4;
            *(float4*)&h2n[im][i0] = hg[i];
        }
    }
    __syncthreads();

    const int jg = tid >> 2, im0 = (tid & 3) * 4;

    if (jg < 30) {  // FC1: 320 -> 120
        union { float4 v; float f[4]; } bv;
        bv.v = *(const float4*)(Lb1 + jg * 4);
        float acc[4][4];
#pragma unroll
        for (int q = 0; q < 4; ++q)
#pragma unroll
            for (int p = 0; p < 4; ++p) acc[q][p] = bv.f[q];
#pragma unroll 4
        for (int i = 0; i < 320; ++i) {
            union { float4 v; float f[4]; } w;
            w.v = *(const float4*)(L1 + i * 120 + jg * 4);
            float h0 = h2n[im0 + 0][i], h1 = h2n[im0 + 1][i];
            float h2v = h2n[im0 + 2][i], h3 = h2n[im0 + 3][i];
#pragma unroll
            for (int q = 0; q < 4; ++q) {
                acc[q][0] += w.f[q] * h0; acc[q][1] += w.f[q] * h1;
                acc[q][2] += w.f[q] * h2v; acc[q][3] += w.f[q] * h3;
            }
        }
#pragma unroll
        for (int q = 0; q < 4; ++q)
#pragma unroll
            for (int p = 0; p < 4; ++p)
                g1n[im0 + p][jg * 4 + q] = sigf(acc[q][p]);
    }
    __syncthreads();

    if (jg < 21) {  // FC2: 120 -> 84
        union { float4 v; float f[4]; } bv;
        bv.v = *(const float4*)(Lb2 + jg * 4);
        float acc[4][4];
#pragma unroll
        for (int q = 0; q < 4; ++q)
#pragma unroll
            for (int p = 0; p < 4; ++p) acc[q][p] = bv.f[q];
#pragma unroll 4
        for (int i = 0; i < 120; ++i) {
            union { float4 v; float f[4]; } w;
            w.v = *(const float4*)(L2p + i * 88 + jg * 4);
            float h0 = g1n[im0 + 0][i], h1 = g1n[im0 + 1][i];
            float h2v = g1n[im0 + 2][i], h3 = g1n[im0 + 3][i];
#pragma unroll
            for (int q = 0; q < 4; ++q) {
                acc[q][0] += w.f[q] * h0; acc[q][1] += w.f[q] * h1;
                acc[q][2] += w.f[q] * h2v; acc[q][3] += w.f[q] * h3;
            }
        }
#pragma unroll
        for (int q = 0; q < 4; ++q)
#pragma unroll
            for (int p = 0; p < 4; ++p)
                g2n[im0 + p][jg * 4 + q] = sigf(acc[q][p]);
    }
    __syncthreads();

    if (tid < 40) {  // FC3: 84 -> 10, 10 j x 4 img-groups
        const int j = tid >> 2, m0 = (tid & 3) * 4;
        float a0 = Lb3[j], a1 = a0, a2 = a0, a3 = a0;
#pragma unroll 4
        for (int i = 0; i < 84; ++i) {
            float w = L3[i * 10 + j];
            a0 += w * g2n[m0 + 0][i]; a1 += w * g2n[m0 + 1][i];
            a2 += w * g2n[m0 + 2][i]; a3 += w * g2n[m0 + 3][i];
        }
        out[(img0 + m0 + 0) * 10 + j] = a0;
        out[(img0 + m0 + 1) * 10 + j] = a1;
        out[(img0 + m0 + 2) * 10 + j] = a2;
        out[(img0 + m0 + 3) * 10 + j] = a3;
    }
}

extern "C" void kernel_launch(void* const* d_in, const int* in_sizes, int n_in,
                              void* d_out, int out_size, void* d_ws, size_t ws_size,
                              hipStream_t stream) {
    const float* x   = (const float*)d_in[0];
    const float* W1  = (const float*)d_in[1];
    const float* b1  = (const float*)d_in[2];
    const float* W2  = (const float*)d_in[3];
    const float* b2  = (const float*)d_in[4];
    const float* L1  = (const float*)d_in[5];
    const float* Lb1 = (const float*)d_in[6];
    const float* L2  = (const float*)d_in[7];
    const float* Lb2 = (const float*)d_in[8];
    const float* L3  = (const float*)d_in[9];
    const float* Lb3 = (const float*)d_in[10];
    float* out = (float*)d_out;

    const int B = in_sizes[0] / 784;  // 8192

    char* ws = (char*)d_ws;
    float* w2q = (float*)ws;                       // 20KB (pad 32KB)
    float* L2p = (float*)(ws + 32768);             // 42.2KB (pad 64KB)
    float* S1g = (float*)(ws + 32768 + 65536);
    float* h2  = (float*)(ws + 32768 + 65536 + (size_t)B * 1320 * 4);

    hipLaunchKernelGGL(k_prep, dim3(59), dim3(256), 0, stream, W2, L2, w2q, L2p);
    hipLaunchKernelGGL(k_conv1, dim3(B / 8), dim3(256), 0, stream, x, W1, b1, S1g);
    hipLaunchKernelGGL(k_conv2, dim3(B / 8), dim3(192), 0, stream, S1g, w2q, b2, h2);
    hipLaunchKernelGGL(k_fc, dim3(B / 16), dim3(128), 0, stream,
                       h2, L1, Lb1, L2p, Lb2, L3, Lb3, out);
}